// Round 1
// baseline (1372.514 us; speedup 1.0000x reference)
//
#include <hip/hip_runtime.h>

// Segment sum: out[index[r], :] += src[r, :], src = (1250000, 64) fp32,
// index in [0, 50000), out = (50000, 64) fp32.
//
// Layout: 16 threads per source row, each owning one float4 (16B) slice.
// - src loads: fully coalesced 16B/lane.
// - index[row]: 16 lanes read the same address -> L1 broadcast.
// - output: 4 atomicAdds to consecutive floats; output is 12.8 MB -> lives
//   in L2/L3, RMW traffic mostly never reaches HBM.

__global__ __launch_bounds__(256) void scatter_add_kernel(
    const float4* __restrict__ src4,
    const int* __restrict__ index,
    float* __restrict__ out,
    int n_vec4)   // = n_rows * 16
{
    int gid = blockIdx.x * blockDim.x + threadIdx.x;
    if (gid >= n_vec4) return;

    int row  = gid >> 4;    // 16 float4 per 64-col row
    int quad = gid & 15;

    int seg = index[row];
    float4 v = src4[gid];

    float* dst = out + (size_t)seg * 64 + quad * 4;
    atomicAdd(dst + 0, v.x);
    atomicAdd(dst + 1, v.y);
    atomicAdd(dst + 2, v.z);
    atomicAdd(dst + 3, v.w);
}

extern "C" void kernel_launch(void* const* d_in, const int* in_sizes, int n_in,
                              void* d_out, int out_size, void* d_ws, size_t ws_size,
                              hipStream_t stream) {
    const float* src   = (const float*)d_in[0];
    const int*   index = (const int*)d_in[1];
    float*       out   = (float*)d_out;

    int n_rows = in_sizes[0] / 64;   // 1,250,000
    int n_vec4 = n_rows * 16;        // 20,000,000 float4 slices

    // Output must start at zero; harness poisons it with 0xAA before each call.
    hipMemsetAsync(d_out, 0, (size_t)out_size * sizeof(float), stream);

    dim3 block(256);
    dim3 grid((n_vec4 + 255) / 256);
    scatter_add_kernel<<<grid, block, 0, stream>>>(
        (const float4*)src, index, out, n_vec4);
}

// Round 2
// 676.371 us; speedup vs baseline: 2.0292x; 2.0292x over previous
//
#include <hip/hip_runtime.h>

// Segment sum via counting-sort + gather (no fp32 atomics).
// src = (1,250,000 x 64) fp32, index in [0, 50000), out = (50000 x 64) fp32.
//
// Round-1 post-mortem: plain atomic scatter ran at 1063us with WRITE_SIZE =
// 1.22 GB for a 12.8 MB output -> device-scope fp32 atomic RMW thrash, not
// HBM-bound (17% of peak). Inverting to a gather removes all fp32 atomics.

// ---------------- Phase 1: histogram ----------------
__global__ __launch_bounds__(256) void hist_kernel(
    const int* __restrict__ index, int* __restrict__ hist, int n)
{
    int i = blockIdx.x * blockDim.x + threadIdx.x;
    if (i < n) atomicAdd(&hist[index[i]], 1);
}

// ---------------- Phase 2: exclusive scan (single block) ----------------
__global__ __launch_bounds__(1024) void scan_kernel(
    const int* __restrict__ hist, int* __restrict__ starts,
    int* __restrict__ cursor, int n)
{
    __shared__ int lds[1024];
    const int tid = threadIdx.x;
    int running = 0;
    for (int base = 0; base < n; base += 1024) {
        int i = base + tid;
        int x = (i < n) ? hist[i] : 0;
        lds[tid] = x;
        __syncthreads();
        for (int off = 1; off < 1024; off <<= 1) {
            int v = (tid >= off) ? lds[tid - off] : 0;
            __syncthreads();
            lds[tid] += v;
            __syncthreads();
        }
        int incl = lds[tid];
        if (i < n) {
            int e = running + incl - x;
            starts[i] = e;
            cursor[i] = e;
        }
        int total = lds[1023];
        __syncthreads();   // everyone read lds[1023] before next chunk writes
        running += total;
    }
    if (tid == 0) starts[n] = running;
}

// ---------------- Phase 3: scatter row ids into buckets ----------------
__global__ __launch_bounds__(256) void bucket_kernel(
    const int* __restrict__ index, int* __restrict__ cursor,
    int* __restrict__ bucket, int n)
{
    int i = blockIdx.x * blockDim.x + threadIdx.x;
    if (i < n) {
        int pos = atomicAdd(&cursor[index[i]], 1);
        bucket[pos] = i;
    }
}

// ---------------- Phase 4: gather-sum, one wave per segment ----------------
__global__ __launch_bounds__(256) void gather_kernel(
    const float4* __restrict__ src4, const int* __restrict__ bucket,
    const int* __restrict__ starts, float4* __restrict__ out4, int nseg)
{
    int wave = (blockIdx.x * blockDim.x + threadIdx.x) >> 6;
    int lane = threadIdx.x & 63;
    if (wave >= nseg) return;

    int beg = starts[wave];
    int end = starts[wave + 1];
    int quad = lane >> 4;   // which of 4 rows-in-flight
    int col  = lane & 15;   // which float4 within the 64-col row

    float4 acc = make_float4(0.f, 0.f, 0.f, 0.f);
    for (int j = beg + quad; j < end; j += 4) {
        int row = bucket[j];
        float4 v = src4[(size_t)row * 16 + col];
        acc.x += v.x; acc.y += v.y; acc.z += v.z; acc.w += v.w;
    }
    // reduce the 4 quad-partials (lanes ^16, ^32 share the same col)
    #pragma unroll
    for (int off = 16; off <= 32; off <<= 1) {
        acc.x += __shfl_xor(acc.x, off, 64);
        acc.y += __shfl_xor(acc.y, off, 64);
        acc.z += __shfl_xor(acc.z, off, 64);
        acc.w += __shfl_xor(acc.w, off, 64);
    }
    if (quad == 0) out4[(size_t)wave * 16 + col] = acc;
}

// ---------------- Fallback: round-1 atomic scatter ----------------
__global__ __launch_bounds__(256) void scatter_add_kernel(
    const float4* __restrict__ src4, const int* __restrict__ index,
    float* __restrict__ out, int n_vec4)
{
    int gid = blockIdx.x * blockDim.x + threadIdx.x;
    if (gid >= n_vec4) return;
    int row = gid >> 4, quad = gid & 15;
    int seg = index[row];
    float4 v = src4[gid];
    float* dst = out + (size_t)seg * 64 + quad * 4;
    atomicAdd(dst + 0, v.x);
    atomicAdd(dst + 1, v.y);
    atomicAdd(dst + 2, v.z);
    atomicAdd(dst + 3, v.w);
}

extern "C" void kernel_launch(void* const* d_in, const int* in_sizes, int n_in,
                              void* d_out, int out_size, void* d_ws, size_t ws_size,
                              hipStream_t stream) {
    const float* src   = (const float*)d_in[0];
    const int*   index = (const int*)d_in[1];
    float*       out   = (float*)d_out;

    const int n_rows = in_sizes[0] / 64;   // 1,250,000
    const int nseg   = out_size / 64;      // 50,000

    // Workspace layout (ints), 256B-aligned sections:
    auto align256 = [](size_t x) { return (x + 255) & ~(size_t)255; };
    size_t off_hist   = 0;
    size_t off_starts = align256(off_hist   + (size_t)nseg * 4);
    size_t off_cursor = align256(off_starts + (size_t)(nseg + 1) * 4);
    size_t off_bucket = align256(off_cursor + (size_t)nseg * 4);
    size_t need       = off_bucket + (size_t)n_rows * 4;

    if (ws_size < need) {
        // Fallback: atomic scatter (correct, slower).
        hipMemsetAsync(d_out, 0, (size_t)out_size * sizeof(float), stream);
        int n_vec4 = n_rows * 16;
        scatter_add_kernel<<<(n_vec4 + 255) / 256, 256, 0, stream>>>(
            (const float4*)src, index, out, n_vec4);
        return;
    }

    char* ws = (char*)d_ws;
    int* hist   = (int*)(ws + off_hist);
    int* starts = (int*)(ws + off_starts);
    int* cursor = (int*)(ws + off_cursor);
    int* bucket = (int*)(ws + off_bucket);

    hipMemsetAsync(hist, 0, (size_t)nseg * 4, stream);

    hist_kernel<<<(n_rows + 255) / 256, 256, 0, stream>>>(index, hist, n_rows);
    scan_kernel<<<1, 1024, 0, stream>>>(hist, starts, cursor, nseg);
    bucket_kernel<<<(n_rows + 255) / 256, 256, 0, stream>>>(index, cursor, bucket, n_rows);

    int n_waves   = nseg;                       // one wave per segment
    int n_threads = n_waves * 64;
    gather_kernel<<<(n_threads + 255) / 256, 256, 0, stream>>>(
        (const float4*)src, bucket, starts, (float4*)out, nseg);
}

// Round 4
// 540.123 us; speedup vs baseline: 2.5411x; 1.2523x over previous
//
#include <hip/hip_runtime.h>

// Segment sum via fixed-capacity bucketing + gather (no fp32 atomics, no scan).
// src = (1,250,000 x 64) fp32, index in [0, 50000), out = (50000 x 64) fp32.
//
// R1: atomic scatter = 1063us, WRITE_SIZE 1.22 GB (atomic RMW thrash).
// R2: gather + exact counting sort = 676us, but single-block scan ate ~540us.
// R3 FAILED: __shfl inside a quad-divergent loop -> ds_bpermute reads from
//   inactive (exited) lanes = undefined. Fix: wave-uniform trip count, all
//   lanes execute the shfl, predicate only the load/accumulate.

#define CAP 64
#define OVF_CAP 8192

// ---- Phase 1: scatter row ids into fixed-capacity buckets ----
__global__ __launch_bounds__(256) void bucket_kernel(
    const int* __restrict__ index, int* __restrict__ count,
    int* __restrict__ bucket, int* __restrict__ ovf_n,
    int* __restrict__ ovf_rows, int n)
{
    int i = blockIdx.x * blockDim.x + threadIdx.x;
    if (i >= n) return;
    int seg = index[i];
    int pos = atomicAdd(&count[seg], 1);
    if (pos < CAP) {
        bucket[(size_t)seg * CAP + pos] = i;
    } else {
        int o = atomicAdd(ovf_n, 1);
        if (o < OVF_CAP) ovf_rows[o] = i;
    }
}

// ---- Phase 2: gather-sum, one wave per segment ----
// Each lane preloads one bucket slot (coalesced 256B/wave). Inner loop:
// wave-uniform trip count; ALL 64 lanes execute the __shfl each iteration
// (source lanes always active), only the load/accumulate is predicated.
__global__ __launch_bounds__(256) void gather_kernel(
    const float4* __restrict__ src4, const int* __restrict__ bucket,
    const int* __restrict__ count, float4* __restrict__ out4, int nseg)
{
    int gid  = blockIdx.x * blockDim.x + threadIdx.x;
    int wave = gid >> 6;
    int lane = threadIdx.x & 63;
    if (wave >= nseg) return;   // wave-uniform exit (whole wave leaves together)

    int c = count[wave];
    if (c > CAP) c = CAP;                 // overflow rows handled by ovf_kernel
    int myrow = bucket[(size_t)wave * CAP + lane];  // lanes >= c: garbage, never shfl'd with j<c... (j<c guard below)

    int quad = lane >> 4;                 // 4 rows in flight per wave
    int col  = lane & 15;                 // float4 column within 64-col row

    float4 acc = make_float4(0.f, 0.f, 0.f, 0.f);
    int iters = (c + 3) >> 2;             // wave-uniform: c is wave-uniform
    for (int it = 0; it < iters; ++it) {
        int j = it * 4 + quad;            // j <= 4*iters-1 <= c+2 <= 63
        int row = __shfl(myrow, j, 64);   // all 64 lanes active here
        if (j < c) {
            float4 v = src4[(size_t)row * 16 + col];
            acc.x += v.x; acc.y += v.y; acc.z += v.z; acc.w += v.w;
        }
    }
    // reduce the 4 quad-partials (lanes ^16, ^32 share the same col)
    acc.x += __shfl_xor(acc.x, 16, 64);
    acc.y += __shfl_xor(acc.y, 16, 64);
    acc.z += __shfl_xor(acc.z, 16, 64);
    acc.w += __shfl_xor(acc.w, 16, 64);
    acc.x += __shfl_xor(acc.x, 32, 64);
    acc.y += __shfl_xor(acc.y, 32, 64);
    acc.z += __shfl_xor(acc.z, 32, 64);
    acc.w += __shfl_xor(acc.w, 32, 64);

    if (quad == 0) out4[(size_t)wave * 16 + col] = acc;   // every seg written once
}

// ---- Phase 3: rare overflow rows -> atomic scatter (after gather) ----
__global__ __launch_bounds__(256) void ovf_kernel(
    const float4* __restrict__ src4, const int* __restrict__ index,
    const int* __restrict__ ovf_n, const int* __restrict__ ovf_rows,
    float* __restrict__ out)
{
    int n = *ovf_n;
    if (n > OVF_CAP) n = OVF_CAP;
    int g16    = (blockIdx.x * blockDim.x + threadIdx.x) >> 4;
    int col    = threadIdx.x & 15;
    int stride = (gridDim.x * blockDim.x) >> 4;
    for (int i = g16; i < n; i += stride) {
        int row = ovf_rows[i];
        int seg = index[row];
        float4 v = src4[(size_t)row * 16 + col];
        float* dst = out + (size_t)seg * 64 + col * 4;
        atomicAdd(dst + 0, v.x);
        atomicAdd(dst + 1, v.y);
        atomicAdd(dst + 2, v.z);
        atomicAdd(dst + 3, v.w);
    }
}

// ---- Fallback: plain atomic scatter (if ws too small) ----
__global__ __launch_bounds__(256) void scatter_add_kernel(
    const float4* __restrict__ src4, const int* __restrict__ index,
    float* __restrict__ out, int n_vec4)
{
    int gid = blockIdx.x * blockDim.x + threadIdx.x;
    if (gid >= n_vec4) return;
    int row = gid >> 4, quad = gid & 15;
    int seg = index[row];
    float4 v = src4[gid];
    float* dst = out + (size_t)seg * 64 + quad * 4;
    atomicAdd(dst + 0, v.x);
    atomicAdd(dst + 1, v.y);
    atomicAdd(dst + 2, v.z);
    atomicAdd(dst + 3, v.w);
}

extern "C" void kernel_launch(void* const* d_in, const int* in_sizes, int n_in,
                              void* d_out, int out_size, void* d_ws, size_t ws_size,
                              hipStream_t stream) {
    const float* src   = (const float*)d_in[0];
    const int*   index = (const int*)d_in[1];
    float*       out   = (float*)d_out;

    const int n_rows = in_sizes[0] / 64;   // 1,250,000
    const int nseg   = out_size / 64;      // 50,000

    // Workspace layout: [count nseg][ovf_n 1][ovf_rows OVF_CAP][bucket nseg*CAP]
    auto align256 = [](size_t x) { return (x + 255) & ~(size_t)255; };
    size_t off_count  = 0;
    size_t off_ovfr   = align256(off_count + (size_t)(nseg + 1) * 4);
    size_t off_bucket = align256(off_ovfr + (size_t)OVF_CAP * 4);
    size_t need       = off_bucket + (size_t)nseg * CAP * 4;

    if (ws_size < need) {
        hipMemsetAsync(d_out, 0, (size_t)out_size * sizeof(float), stream);
        int n_vec4 = n_rows * 16;
        scatter_add_kernel<<<(n_vec4 + 255) / 256, 256, 0, stream>>>(
            (const float4*)src, index, out, n_vec4);
        return;
    }

    char* ws = (char*)d_ws;
    int* count    = (int*)(ws + off_count);
    int* ovf_n    = count + nseg;          // right after count (memset together)
    int* ovf_rows = (int*)(ws + off_ovfr);
    int* bucket   = (int*)(ws + off_bucket);

    hipMemsetAsync(count, 0, (size_t)(nseg + 1) * 4, stream);

    bucket_kernel<<<(n_rows + 255) / 256, 256, 0, stream>>>(
        index, count, bucket, ovf_n, ovf_rows, n_rows);

    int n_threads = nseg * 64;             // one wave per segment
    gather_kernel<<<(n_threads + 255) / 256, 256, 0, stream>>>(
        (const float4*)src, bucket, count, (float4*)out, nseg);

    ovf_kernel<<<8, 256, 0, stream>>>(
        (const float4*)src, index, ovf_n, ovf_rows, out);
}

// Round 5
// 517.631 us; speedup vs baseline: 2.6515x; 1.0435x over previous
//
#include <hip/hip_runtime.h>

// Segment sum via fixed-capacity bucketing + gather (no fp32 atomics, no scan).
// src = (1,250,000 x 64) fp32, index in [0, 50000), out = (50000 x 64) fp32.
//
// R1: atomic scatter = 1063us kernel, WRITE_SIZE 1.22 GB (atomic RMW thrash).
// R2: gather + exact counting sort = 676us, single-block scan ate ~240us.
// R3 FAILED: __shfl in a quad-divergent loop (inactive-lane bpermute = undef).
// R4: wave-uniform trip count -> 540us total (~305us is harness reset fills).
// R5: gather 2-wide load pairing (2 loads in flight/wave), nontemporal src
//     loads + bucket/out stores, int2-vectorized bucket build.

#define CAP 64
#define OVF_CAP 65536

typedef float v4f __attribute__((ext_vector_type(4)));

// ---- Phase 1: scatter row ids into fixed-capacity buckets (2 rows/thread) ----
__global__ __launch_bounds__(256) void bucket_kernel(
    const int2* __restrict__ index2, int* __restrict__ count,
    int* __restrict__ bucket, int* __restrict__ ovf_n,
    int* __restrict__ ovf_rows, int n2)
{
    int i = blockIdx.x * blockDim.x + threadIdx.x;
    if (i >= n2) return;
    int2 ix = index2[i];
    int row0 = i * 2, row1 = i * 2 + 1;

    int pos0 = atomicAdd(&count[ix.x], 1);
    if (pos0 < CAP) {
        __builtin_nontemporal_store(row0, &bucket[(size_t)ix.x * CAP + pos0]);
    } else {
        int o = atomicAdd(ovf_n, 1);
        if (o < OVF_CAP) ovf_rows[o] = row0;
    }
    int pos1 = atomicAdd(&count[ix.y], 1);
    if (pos1 < CAP) {
        __builtin_nontemporal_store(row1, &bucket[(size_t)ix.y * CAP + pos1]);
    } else {
        int o = atomicAdd(ovf_n, 1);
        if (o < OVF_CAP) ovf_rows[o] = row1;
    }
}

// ---- Phase 2: gather-sum, one wave per segment ----
// Lane preloads one bucket slot (coalesced 256B/wave); inner loop broadcasts
// row ids via shfl with a wave-uniform trip count (ALL lanes execute the
// shfl; only loads/accumulates are predicated). Paired 2-wide so two src
// loads are in flight before either accumulate. In the paired main loop
// j0 < c always holds (c > 4*(iters-1) => j0 <= 4*iters-5 <= c-2).
__global__ __launch_bounds__(256) void gather_kernel(
    const v4f* __restrict__ src4, const int* __restrict__ bucket,
    const int* __restrict__ count, v4f* __restrict__ out4, int nseg)
{
    int gid  = blockIdx.x * blockDim.x + threadIdx.x;
    int wave = gid >> 6;
    int lane = threadIdx.x & 63;
    if (wave >= nseg) return;   // wave-uniform exit

    int c = count[wave];
    if (c > CAP) c = CAP;                 // overflow handled by ovf_kernel
    int myrow = bucket[(size_t)wave * CAP + lane];

    int quad = lane >> 4;                 // 4 rows in flight per wave
    int col  = lane & 15;                 // float4 column within 64-col row

    v4f acc = {0.f, 0.f, 0.f, 0.f};
    int iters = (c + 3) >> 2;             // wave-uniform
    int it = 0;
    for (; it + 1 < iters; it += 2) {
        int j0 = (it << 2) + quad;        // always < c in this loop
        int j1 = j0 + 4;
        int r0 = __shfl(myrow, j0, 64);   // all 64 lanes active
        int r1 = __shfl(myrow, j1, 64);
        v4f v0 = __builtin_nontemporal_load(&src4[(size_t)r0 * 16 + col]);
        v4f v1 = {0.f, 0.f, 0.f, 0.f};
        if (j1 < c) v1 = __builtin_nontemporal_load(&src4[(size_t)r1 * 16 + col]);
        acc += v0;
        acc += v1;
    }
    if (it < iters) {
        int j = (it << 2) + quad;
        int r = __shfl(myrow, j, 64);
        if (j < c) acc += __builtin_nontemporal_load(&src4[(size_t)r * 16 + col]);
    }

    // reduce the 4 quad-partials (lanes ^16, ^32 share the same col)
    acc.x += __shfl_xor(acc.x, 16, 64);
    acc.y += __shfl_xor(acc.y, 16, 64);
    acc.z += __shfl_xor(acc.z, 16, 64);
    acc.w += __shfl_xor(acc.w, 16, 64);
    acc.x += __shfl_xor(acc.x, 32, 64);
    acc.y += __shfl_xor(acc.y, 32, 64);
    acc.z += __shfl_xor(acc.z, 32, 64);
    acc.w += __shfl_xor(acc.w, 32, 64);

    if (quad == 0)
        __builtin_nontemporal_store(acc, &out4[(size_t)wave * 16 + col]);
}

// ---- Phase 3: rare overflow rows -> atomic scatter (after gather) ----
__global__ __launch_bounds__(256) void ovf_kernel(
    const v4f* __restrict__ src4, const int* __restrict__ index,
    const int* __restrict__ ovf_n, const int* __restrict__ ovf_rows,
    float* __restrict__ out)
{
    int n = *ovf_n;
    if (n > OVF_CAP) n = OVF_CAP;
    int g16    = (blockIdx.x * blockDim.x + threadIdx.x) >> 4;
    int col    = threadIdx.x & 15;
    int stride = (gridDim.x * blockDim.x) >> 4;
    for (int i = g16; i < n; i += stride) {
        int row = ovf_rows[i];
        int seg = index[row];
        v4f v = src4[(size_t)row * 16 + col];
        float* dst = out + (size_t)seg * 64 + col * 4;
        atomicAdd(dst + 0, v.x);
        atomicAdd(dst + 1, v.y);
        atomicAdd(dst + 2, v.z);
        atomicAdd(dst + 3, v.w);
    }
}

// ---- Fallback: plain atomic scatter (if ws too small) ----
__global__ __launch_bounds__(256) void scatter_add_kernel(
    const float4* __restrict__ src4, const int* __restrict__ index,
    float* __restrict__ out, int n_vec4)
{
    int gid = blockIdx.x * blockDim.x + threadIdx.x;
    if (gid >= n_vec4) return;
    int row = gid >> 4, quad = gid & 15;
    int seg = index[row];
    float4 v = src4[gid];
    float* dst = out + (size_t)seg * 64 + quad * 4;
    atomicAdd(dst + 0, v.x);
    atomicAdd(dst + 1, v.y);
    atomicAdd(dst + 2, v.z);
    atomicAdd(dst + 3, v.w);
}

extern "C" void kernel_launch(void* const* d_in, const int* in_sizes, int n_in,
                              void* d_out, int out_size, void* d_ws, size_t ws_size,
                              hipStream_t stream) {
    const float* src   = (const float*)d_in[0];
    const int*   index = (const int*)d_in[1];
    float*       out   = (float*)d_out;

    const int n_rows = in_sizes[0] / 64;   // 1,250,000
    const int nseg   = out_size / 64;      // 50,000

    // Workspace: [count nseg][ovf_n 1][ovf_rows OVF_CAP][bucket nseg*CAP]
    auto align256 = [](size_t x) { return (x + 255) & ~(size_t)255; };
    size_t off_count  = 0;
    size_t off_ovfr   = align256(off_count + (size_t)(nseg + 1) * 4);
    size_t off_bucket = align256(off_ovfr + (size_t)OVF_CAP * 4);
    size_t need       = off_bucket + (size_t)nseg * CAP * 4;

    if (ws_size < need || (n_rows & 1)) {
        hipMemsetAsync(d_out, 0, (size_t)out_size * sizeof(float), stream);
        int n_vec4 = n_rows * 16;
        scatter_add_kernel<<<(n_vec4 + 255) / 256, 256, 0, stream>>>(
            (const float4*)src, index, out, n_vec4);
        return;
    }

    char* ws = (char*)d_ws;
    int* count    = (int*)(ws + off_count);
    int* ovf_n    = count + nseg;          // contiguous with count (one memset)
    int* ovf_rows = (int*)(ws + off_ovfr);
    int* bucket   = (int*)(ws + off_bucket);

    hipMemsetAsync(count, 0, (size_t)(nseg + 1) * 4, stream);

    int n2 = n_rows / 2;
    bucket_kernel<<<(n2 + 255) / 256, 256, 0, stream>>>(
        (const int2*)index, count, bucket, ovf_n, ovf_rows, n2);

    int n_threads = nseg * 64;             // one wave per segment
    gather_kernel<<<(n_threads + 255) / 256, 256, 0, stream>>>(
        (const v4f*)src, bucket, count, (v4f*)out, nseg);

    ovf_kernel<<<8, 256, 0, stream>>>(
        (const v4f*)src, index, ovf_n, ovf_rows, out);
}